// Round 13
// baseline (89.072 us; speedup 1.0000x reference)
//
#include <hip/hip_runtime.h>
#include <math.h>

#define NQ 14
#define DIM (1 << NQ)      // 16384 amplitudes
#define NT 512             // 8 waves per block; ~133 KB LDS -> 1 block/CU
#define TA 32              // amplitudes per thread (5-bit tile)
#define NW (NT / 64)
#define PDIM (DIM + DIM / 32)   // padded: one spare cf2 per 32

// ---- compile-time for ----
template <int J> struct IC { static constexpr int v = J; };
template <int N, typename F>
__device__ __forceinline__ void sfor(F&& f) {
    if constexpr (N > 0) { sfor<N - 1>(f); f(IC<N - 1>{}); }
}

// ---- complex amplitude as a 2-wide ext_vector ----
typedef float cf2 __attribute__((ext_vector_type(2)));

// ---- state: 32 INDEPENDENT cf2 SSA values (compile-time indexed).
// r8: one 64-wide vector serializes loads. r10: XOR-swizzle addressing
// spills at the hard 128-VGPR clamp. Independent cf2 + additive pad keeps
// ds_read_b64 landing directly in a register pair with immediate offsets. ----
struct St {
    cf2 a0, a1, a2, a3, a4, a5, a6, a7, a8, a9, a10, a11, a12, a13, a14, a15,
        a16, a17, a18, a19, a20, a21, a22, a23, a24, a25, a26, a27, a28, a29, a30, a31;
};
template <int J> __device__ __forceinline__ cf2& amp(St& s);
#define AMP_GET(J) template <> __device__ __forceinline__ cf2& amp<J>(St& s) { return s.a##J; }
AMP_GET(0)  AMP_GET(1)  AMP_GET(2)  AMP_GET(3)  AMP_GET(4)  AMP_GET(5)  AMP_GET(6)  AMP_GET(7)
AMP_GET(8)  AMP_GET(9)  AMP_GET(10) AMP_GET(11) AMP_GET(12) AMP_GET(13) AMP_GET(14) AMP_GET(15)
AMP_GET(16) AMP_GET(17) AMP_GET(18) AMP_GET(19) AMP_GET(20) AMP_GET(21) AMP_GET(22) AMP_GET(23)
AMP_GET(24) AMP_GET(25) AMP_GET(26) AMP_GET(27) AMP_GET(28) AMP_GET(29) AMP_GET(30) AMP_GET(31)

// (x,y) -> (y,-x)
__device__ __forceinline__ cf2 swapneg(cf2 v) { cf2 r; r.x = v.y; r.y = -v.x; return r; }

// ---- additive padded layout: phys(idx) = idx + (idx>>5); base/offset bits
// disjoint -> phys splits; every LDS access = base + compile-time const.
// All tiles: 32 bank-pairs x 2 lanes -> conflict-free b64. ----
__host__ __device__ constexpr int pad(int idx) { return idx + (idx >> 5); }

template <int P0, int P1, int P2, int P3, int P4>
struct Tile5 {
    static constexpr int PMASK = (1 << P0) | (1 << P1) | (1 << P2) | (1 << P3) | (1 << P4);
    static __device__ __forceinline__ int base_idx(int t) {
        int idx = 0, tb = 0;
#pragma unroll
        for (int p = 0; p < NQ; ++p)
            if (!((PMASK >> p) & 1)) { idx |= ((t >> tb) & 1) << p; ++tb; }
        return idx;
    }
    static constexpr int off(int j) {
        return ((j & 1) << P0) | (((j >> 1) & 1) << P1) | (((j >> 2) & 1) << P2) |
               (((j >> 3) & 1) << P3) | (((j >> 4) & 1) << P4);
    }
    static constexpr int poff(int j) { return pad(off(j)); }
};

// qubit q lives at bit position 13-q.
using TileR1 = Tile5<9, 10, 11, 12, 13>;   // l4..l0 = q0,q1,q2,q3,q4
using TileR2 = Tile5<5, 6, 7, 8, 9>;       // l4..l0 = q4,q5,q6,q7,q8
using TileR3 = Tile5<1, 2, 3, 4, 5>;       // l4..l0 = q8,q9,q10,q11,q12
using TileR4 = Tile5<0, 1, 13, 12, 11>;    // l0=q13, l1=q12, l2=q0, l3=q1, l4=q2

template <class T>
__device__ __forceinline__ void load_tile(const cf2* s, int pb, St& st) {
    sfor<TA>([&](auto jc) {
        constexpr int j = decltype(jc)::v;
        amp<j>(st) = s[pb + T::poff(j)];
    });
}
template <class T>
__device__ __forceinline__ void store_tile(cf2* s, int pb, St& st) {
    sfor<TA>([&](auto jc) {
        constexpr int j = decltype(jc)::v;
        s[pb + T::poff(j)] = amp<j>(st);
    });
}

// RY: [[c,-s],[s,c]]
template <int LB>
__device__ __forceinline__ void g_ry(St& st, float c, float s) {
    sfor<TA>([&](auto jc) {
        constexpr int j = decltype(jc)::v;
        if constexpr (!(j & (1 << LB))) {
            constexpr int k = j | (1 << LB);
            cf2 aj = amp<j>(st), ak = amp<k>(st);
            amp<j>(st) = c * aj - s * ak;
            amp<k>(st) = s * aj + c * ak;
        }
    });
}
// RX: [[c,-is],[-is,c]]
template <int LB>
__device__ __forceinline__ void g_rx(St& st, float c, float s) {
    sfor<TA>([&](auto jc) {
        constexpr int j = decltype(jc)::v;
        if constexpr (!(j & (1 << LB))) {
            constexpr int k = j | (1 << LB);
            cf2 aj = amp<j>(st), ak = amp<k>(st);
            amp<j>(st) = c * aj + s * swapneg(ak);
            amp<k>(st) = c * ak + s * swapneg(aj);
        }
    });
}
// CNOT control local LC, target local LT: pure SSA rename (free)
template <int LC, int LT>
__device__ __forceinline__ void g_cnot(St& st) {
    sfor<TA>([&](auto jc) {
        constexpr int j = decltype(jc)::v;
        if constexpr (((j >> LC) & 1) && !((j >> LT) & 1)) {
            constexpr int k = j | (1 << LT);
            cf2 t = amp<j>(st);
            amp<j>(st) = amp<k>(st);
            amp<k>(st) = t;
        }
    });
}

// Per layer, 4 rounds (ring CNOTs (q0,q1)..(q12,q13)(q13,q0)); embedding RY
// folded into layer 0. r13 changes vs r12 (both semantics-preserving):
//  1. Coefficients are hoisted into registers BEFORE load_tile — inline
//     sC[i]/sS[i] reads were ds_read_b32s issued AFTER the 32 tile loads,
//     and in-order lgkmcnt made the first gate wait drain ALL tile loads.
//  2. Rotations applied low-register-bit-first (rx<0> pairs (0,1)) so
//     compute can start after 2 loads (fine-grained lgkmcnt overlap).
//     Rotations on distinct qubits commute; CNOT chain order unchanged.
__global__ void __launch_bounds__(NT) qsim_kernel(const float* __restrict__ x,
                                                  const float* __restrict__ w,
                                                  float* __restrict__ out) {
    __shared__ cf2 sSt[PDIM];            // ~132 KB padded
    __shared__ float sC[56], sS[56];     // [0..13]=RY embed, 14+l*14+q = RX
    __shared__ float sRed[NW][NQ];

    const int tid = threadIdx.x;
    const int b = blockIdx.x;

    if (tid < 14) {
        float th = tanhf(x[b * NQ + tid]) * 1.57079632679489662f;
        sC[tid] = cosf(th); sS[tid] = sinf(th);
    } else if (tid < 56) {
        float th = w[tid - 14] * 0.5f;
        sC[tid] = cosf(th); sS[tid] = sinf(th);
    }

    const int pb1 = pad(TileR1::base_idx(tid));
    const int pb2 = pad(TileR2::base_idx(tid));
    const int pb3 = pad(TileR3::base_idx(tid));
    const int pb4 = pad(TileR4::base_idx(tid));

    __syncthreads();

    St st;

    // ================= layer 0 (embedding folded in) =================
    {   // R1: init |0..0> + RY q0-4 + RX q0-4 + chain CNOTs (no loads)
        float cy0 = sC[0], sy0 = sS[0], cy1 = sC[1], sy1 = sS[1], cy2 = sC[2], sy2 = sS[2];
        float cy3 = sC[3], sy3 = sS[3], cy4 = sC[4], sy4 = sS[4];
        float cx0 = sC[14], sx0 = sS[14], cx1 = sC[15], sx1 = sS[15], cx2 = sC[16], sx2 = sS[16];
        float cx3 = sC[17], sx3 = sS[17], cx4 = sC[18], sx4 = sS[18];
        sfor<TA>([&](auto jc) {
            constexpr int j = decltype(jc)::v;
            cf2 z; z.x = 0.f; z.y = 0.f;
            amp<j>(st) = z;
        });
        if (tid == 0) amp<0>(st).x = 1.f;
        g_ry<0>(st, cy4, sy4); g_ry<1>(st, cy3, sy3); g_ry<2>(st, cy2, sy2);
        g_ry<3>(st, cy1, sy1); g_ry<4>(st, cy0, sy0);
        g_rx<0>(st, cx4, sx4); g_rx<1>(st, cx3, sx3); g_rx<2>(st, cx2, sx2);
        g_rx<3>(st, cx1, sx1); g_rx<4>(st, cx0, sx0);
        g_cnot<4, 3>(st); g_cnot<3, 2>(st); g_cnot<2, 1>(st); g_cnot<1, 0>(st);
        store_tile<TileR1>(sSt, pb1, st);
    }
    __syncthreads();
    {   // R2: RY q5-8 + RX q5-8 + CNOT(q4,q5)..(q7,q8)
        float cy5 = sC[5], sy5 = sS[5], cy6 = sC[6], sy6 = sS[6];
        float cy7 = sC[7], sy7 = sS[7], cy8 = sC[8], sy8 = sS[8];
        float cx5 = sC[19], sx5 = sS[19], cx6 = sC[20], sx6 = sS[20];
        float cx7 = sC[21], sx7 = sS[21], cx8 = sC[22], sx8 = sS[22];
        load_tile<TileR2>(sSt, pb2, st);
        g_ry<0>(st, cy8, sy8); g_ry<1>(st, cy7, sy7); g_ry<2>(st, cy6, sy6); g_ry<3>(st, cy5, sy5);
        g_rx<0>(st, cx8, sx8); g_rx<1>(st, cx7, sx7); g_rx<2>(st, cx6, sx6); g_rx<3>(st, cx5, sx5);
        g_cnot<4, 3>(st); g_cnot<3, 2>(st); g_cnot<2, 1>(st); g_cnot<1, 0>(st);
        store_tile<TileR2>(sSt, pb2, st);
    }
    __syncthreads();
    {   // R3: RY q9-12 + RX q9-12 + CNOT(q8,q9)..(q11,q12)
        float cy9 = sC[9], sy9 = sS[9], cyA = sC[10], syA = sS[10];
        float cyB = sC[11], syB = sS[11], cyC = sC[12], syC = sS[12];
        float cx9 = sC[23], sx9 = sS[23], cxA = sC[24], sxA = sS[24];
        float cxB = sC[25], sxB = sS[25], cxC = sC[26], sxC = sS[26];
        load_tile<TileR3>(sSt, pb3, st);
        g_ry<0>(st, cyC, syC); g_ry<1>(st, cyB, syB); g_ry<2>(st, cyA, syA); g_ry<3>(st, cy9, sy9);
        g_rx<0>(st, cxC, sxC); g_rx<1>(st, cxB, sxB); g_rx<2>(st, cxA, sxA); g_rx<3>(st, cx9, sx9);
        g_cnot<4, 3>(st); g_cnot<3, 2>(st); g_cnot<2, 1>(st); g_cnot<1, 0>(st);
        store_tile<TileR3>(sSt, pb3, st);
    }
    __syncthreads();
    {   // R4: RY q13 + RX q13 + CNOT(q12,q13)(q13,q0)
        float cyD = sC[13], syD = sS[13], cxD = sC[27], sxD = sS[27];
        load_tile<TileR4>(sSt, pb4, st);
        g_ry<0>(st, cyD, syD);
        g_rx<0>(st, cxD, sxD);
        g_cnot<1, 0>(st); g_cnot<0, 2>(st);
        store_tile<TileR4>(sSt, pb4, st);
    }
    __syncthreads();

    // ================= layers 1,2 =================
#pragma unroll 1
    for (int l = 1; l < 3; ++l) {
        const int s0 = 14 + l * NQ;
        {   // R1
            float c0 = sC[s0 + 0], t0 = sS[s0 + 0], c1 = sC[s0 + 1], t1 = sS[s0 + 1];
            float c2 = sC[s0 + 2], t2 = sS[s0 + 2], c3 = sC[s0 + 3], t3 = sS[s0 + 3];
            float c4 = sC[s0 + 4], t4 = sS[s0 + 4];
            load_tile<TileR1>(sSt, pb1, st);
            g_rx<0>(st, c4, t4); g_rx<1>(st, c3, t3); g_rx<2>(st, c2, t2);
            g_rx<3>(st, c1, t1); g_rx<4>(st, c0, t0);
            g_cnot<4, 3>(st); g_cnot<3, 2>(st); g_cnot<2, 1>(st); g_cnot<1, 0>(st);
            store_tile<TileR1>(sSt, pb1, st);
        }
        __syncthreads();
        {   // R2
            float c5 = sC[s0 + 5], t5 = sS[s0 + 5], c6 = sC[s0 + 6], t6 = sS[s0 + 6];
            float c7 = sC[s0 + 7], t7 = sS[s0 + 7], c8 = sC[s0 + 8], t8 = sS[s0 + 8];
            load_tile<TileR2>(sSt, pb2, st);
            g_rx<0>(st, c8, t8); g_rx<1>(st, c7, t7); g_rx<2>(st, c6, t6); g_rx<3>(st, c5, t5);
            g_cnot<4, 3>(st); g_cnot<3, 2>(st); g_cnot<2, 1>(st); g_cnot<1, 0>(st);
            store_tile<TileR2>(sSt, pb2, st);
        }
        __syncthreads();
        {   // R3
            float c9 = sC[s0 + 9], t9 = sS[s0 + 9], cA = sC[s0 + 10], tA = sS[s0 + 10];
            float cB = sC[s0 + 11], tB = sS[s0 + 11], cC = sC[s0 + 12], tC = sS[s0 + 12];
            load_tile<TileR3>(sSt, pb3, st);
            g_rx<0>(st, cC, tC); g_rx<1>(st, cB, tB); g_rx<2>(st, cA, tA); g_rx<3>(st, c9, t9);
            g_cnot<4, 3>(st); g_cnot<3, 2>(st); g_cnot<2, 1>(st); g_cnot<1, 0>(st);
            store_tile<TileR3>(sSt, pb3, st);
        }
        __syncthreads();
        {   // R4
            float cD = sC[s0 + 13], tD = sS[s0 + 13];
            load_tile<TileR4>(sSt, pb4, st);
            g_rx<0>(st, cD, tD);
            g_cnot<1, 0>(st); g_cnot<0, 2>(st);
            if (l == 1) store_tile<TileR4>(sSt, pb4, st);
        }
        if (l == 1) __syncthreads();
    }

    // ====== expvals from final registers (TileR4: l0=q13,l1=q12,l2=q0,l3=q1,l4=q2) ======
    float Stot = 0.f, S0 = 0.f, S1 = 0.f, S2 = 0.f, S3 = 0.f, S4 = 0.f;
    sfor<TA>([&](auto jc) {
        constexpr int j = decltype(jc)::v;
        cf2 v = amp<j>(st);
        float pj = v.x * v.x + v.y * v.y;
        Stot += pj;
        S0 += (j & 1)  ? -pj : pj;   // q13
        S1 += (j & 2)  ? -pj : pj;   // q12
        S2 += (j & 4)  ? -pj : pj;   // q0
        S3 += (j & 8)  ? -pj : pj;   // q1
        S4 += (j & 16) ? -pj : pj;   // q2
    });
    float ev[NQ];
    ev[0] = S2; ev[1] = S3; ev[2] = S4; ev[12] = S1; ev[13] = S0;
#pragma unroll
    for (int q = 3; q <= 11; ++q)    // q3..q11 <- tid bit (11-q)
        ev[q] = ((tid >> (11 - q)) & 1) ? -Stot : Stot;

#pragma unroll
    for (int q = 0; q < NQ; ++q) {
#pragma unroll
        for (int o = 32; o > 0; o >>= 1) ev[q] += __shfl_down(ev[q], o);
    }
    const int wv = tid >> 6, ln = tid & 63;
    if (ln == 0) {
#pragma unroll
        for (int q = 0; q < NQ; ++q) sRed[wv][q] = ev[q];
    }
    __syncthreads();
    if (tid < NQ) {
        float acc = 0.f;
#pragma unroll
        for (int k = 0; k < NW; ++k) acc += sRed[k][tid];
        out[b * NQ + tid] = acc;
    }
}

extern "C" void kernel_launch(void* const* d_in, const int* in_sizes, int n_in,
                              void* d_out, int out_size, void* d_ws, size_t ws_size,
                              hipStream_t stream) {
    const float* x = (const float*)d_in[0];   // (256, 14) float32
    const float* w = (const float*)d_in[1];   // (3, 14) float32
    float* out = (float*)d_out;               // (256, 14) float32
    qsim_kernel<<<256, NT, 0, stream>>>(x, w, out);
}

// Round 14
// 82.155 us; speedup vs baseline: 1.0842x; 1.0842x over previous
//
#include <hip/hip_runtime.h>
#include <math.h>

#define NQ 14
#define DIM (1 << NQ)      // 16384 amplitudes
#define NT 512             // 8 waves per block; ~133 KB LDS -> 1 block/CU
#define TA 32              // amplitudes per thread (5-bit tile)
#define NW (NT / 64)
#define PDIM (DIM + DIM / 32)   // padded: one spare cf2 per 32

// ---- compile-time for ----
template <int J> struct IC { static constexpr int v = J; };
template <int N, typename F>
__device__ __forceinline__ void sfor(F&& f) {
    if constexpr (N > 0) { sfor<N - 1>(f); f(IC<N - 1>{}); }
}

// ---- complex amplitude as a 2-wide ext_vector (one 64-bit VGPR pair) ----
typedef float cf2 __attribute__((ext_vector_type(2)));

// ---- packed fp32 gate math (r12 falsification: clang does NOT lower
// <2 x float> arithmetic to v_pk_*_f32 — VALUBusy stayed 47%). Hand-rolled
// VOP3P asm: full-rate 2x FP32/instr, and op_sel/neg_hi implement RX's
// swap-negate inside the multiply for free. ----
// t = { s.lo * ak.hi , -(s.hi * ak.lo) }   [= s * swapneg(ak)]
__device__ __forceinline__ cf2 pk_mul_swapneg(cf2 s, cf2 ak) {
    cf2 t;
    asm("v_pk_mul_f32 %0, %1, %2 op_sel:[0,1] op_sel_hi:[1,0] neg_hi:[0,1]"
        : "=v"(t) : "v"(s), "v"(ak));
    return t;
}
__device__ __forceinline__ cf2 pk_mul(cf2 a, cf2 b) {
    cf2 t;
    asm("v_pk_mul_f32 %0, %1, %2" : "=v"(t) : "v"(a), "v"(b));
    return t;
}
__device__ __forceinline__ cf2 pk_fma(cf2 a, cf2 b, cf2 c) {
    cf2 d;
    asm("v_pk_fma_f32 %0, %1, %2, %3" : "=v"(d) : "v"(a), "v"(b), "v"(c));
    return d;
}
// d = a*b - c
__device__ __forceinline__ cf2 pk_fms(cf2 a, cf2 b, cf2 c) {
    cf2 d;
    asm("v_pk_fma_f32 %0, %1, %2, %3 neg_lo:[0,0,1] neg_hi:[0,0,1]"
        : "=v"(d) : "v"(a), "v"(b), "v"(c));
    return d;
}

// ---- state: 32 INDEPENDENT cf2 SSA values (compile-time indexed).
// r8: one 64-wide vector serializes loads. r10: XOR-swizzle addressing
// spills at the hard 128-VGPR clamp. Independent cf2 + additive pad keeps
// ds_read_b64 landing directly in a register pair with immediate offsets. ----
struct St {
    cf2 a0, a1, a2, a3, a4, a5, a6, a7, a8, a9, a10, a11, a12, a13, a14, a15,
        a16, a17, a18, a19, a20, a21, a22, a23, a24, a25, a26, a27, a28, a29, a30, a31;
};
template <int J> __device__ __forceinline__ cf2& amp(St& s);
#define AMP_GET(J) template <> __device__ __forceinline__ cf2& amp<J>(St& s) { return s.a##J; }
AMP_GET(0)  AMP_GET(1)  AMP_GET(2)  AMP_GET(3)  AMP_GET(4)  AMP_GET(5)  AMP_GET(6)  AMP_GET(7)
AMP_GET(8)  AMP_GET(9)  AMP_GET(10) AMP_GET(11) AMP_GET(12) AMP_GET(13) AMP_GET(14) AMP_GET(15)
AMP_GET(16) AMP_GET(17) AMP_GET(18) AMP_GET(19) AMP_GET(20) AMP_GET(21) AMP_GET(22) AMP_GET(23)
AMP_GET(24) AMP_GET(25) AMP_GET(26) AMP_GET(27) AMP_GET(28) AMP_GET(29) AMP_GET(30) AMP_GET(31)

// ---- additive padded layout: phys(idx) = idx + (idx>>5); base/offset bits
// disjoint -> phys splits; every LDS access = base + compile-time const.
// All tiles: 32 bank-pairs x 2 lanes -> conflict-minimal b64. ----
__host__ __device__ constexpr int pad(int idx) { return idx + (idx >> 5); }

template <int P0, int P1, int P2, int P3, int P4>
struct Tile5 {
    static constexpr int PMASK = (1 << P0) | (1 << P1) | (1 << P2) | (1 << P3) | (1 << P4);
    static __device__ __forceinline__ int base_idx(int t) {
        int idx = 0, tb = 0;
#pragma unroll
        for (int p = 0; p < NQ; ++p)
            if (!((PMASK >> p) & 1)) { idx |= ((t >> tb) & 1) << p; ++tb; }
        return idx;
    }
    static constexpr int off(int j) {
        return ((j & 1) << P0) | (((j >> 1) & 1) << P1) | (((j >> 2) & 1) << P2) |
               (((j >> 3) & 1) << P3) | (((j >> 4) & 1) << P4);
    }
    static constexpr int poff(int j) { return pad(off(j)); }
};

// qubit q lives at bit position 13-q.
using TileR1 = Tile5<9, 10, 11, 12, 13>;   // l4..l0 = q0,q1,q2,q3,q4
using TileR2 = Tile5<5, 6, 7, 8, 9>;       // l4..l0 = q4,q5,q6,q7,q8
using TileR3 = Tile5<1, 2, 3, 4, 5>;       // l4..l0 = q8,q9,q10,q11,q12
using TileR4 = Tile5<0, 1, 13, 12, 11>;    // l0=q13, l1=q12, l2=q0, l3=q1, l4=q2

template <class T>
__device__ __forceinline__ void load_tile(const cf2* s, int pb, St& st) {
    sfor<TA>([&](auto jc) {
        constexpr int j = decltype(jc)::v;
        amp<j>(st) = s[pb + T::poff(j)];
    });
}
template <class T>
__device__ __forceinline__ void store_tile(cf2* s, int pb, St& st) {
    sfor<TA>([&](auto jc) {
        constexpr int j = decltype(jc)::v;
        s[pb + T::poff(j)] = amp<j>(st);
    });
}

// RY: [[c,-s],[s,c]] — aj' = c*aj - s*ak ; ak' = s*aj + c*ak (4 pk instrs/pair)
template <int LB>
__device__ __forceinline__ void g_ry(St& st, cf2 cc, cf2 ss) {
    sfor<TA>([&](auto jc) {
        constexpr int j = decltype(jc)::v;
        if constexpr (!(j & (1 << LB))) {
            constexpr int k = j | (1 << LB);
            cf2 aj = amp<j>(st), ak = amp<k>(st);
            amp<j>(st) = pk_fms(cc, aj, pk_mul(ss, ak));
            amp<k>(st) = pk_fma(ss, aj, pk_mul(cc, ak));
        }
    });
}
// RX: [[c,-is],[-is,c]] — aj' = c*aj + s*swapneg(ak) (4 pk instrs/pair)
template <int LB>
__device__ __forceinline__ void g_rx(St& st, cf2 cc, cf2 ss) {
    sfor<TA>([&](auto jc) {
        constexpr int j = decltype(jc)::v;
        if constexpr (!(j & (1 << LB))) {
            constexpr int k = j | (1 << LB);
            cf2 aj = amp<j>(st), ak = amp<k>(st);
            amp<j>(st) = pk_fma(cc, aj, pk_mul_swapneg(ss, ak));
            amp<k>(st) = pk_fma(cc, ak, pk_mul_swapneg(ss, aj));
        }
    });
}
// CNOT control local LC, target local LT: pure SSA rename (free)
template <int LC, int LT>
__device__ __forceinline__ void g_cnot(St& st) {
    sfor<TA>([&](auto jc) {
        constexpr int j = decltype(jc)::v;
        if constexpr (((j >> LC) & 1) && !((j >> LT) & 1)) {
            constexpr int k = j | (1 << LT);
            cf2 t = amp<j>(st);
            amp<j>(st) = amp<k>(st);
            amp<k>(st) = t;
        }
    });
}

__device__ __forceinline__ cf2 bcast(float v) { cf2 r; r.x = v; r.y = v; return r; }

// Per layer, 4 rounds (ring CNOTs (q0,q1)..(q12,q13)(q13,q0)); embedding RY
// folded into layer 0. Coefficients hoisted before load_tile (r13);
// rotations low-register-bit-first (r13); gate bodies = packed-fp32 asm (r14).
__global__ void __launch_bounds__(NT) qsim_kernel(const float* __restrict__ x,
                                                  const float* __restrict__ w,
                                                  float* __restrict__ out) {
    __shared__ cf2 sSt[PDIM];            // ~132 KB padded
    __shared__ float sC[56], sS[56];     // [0..13]=RY embed, 14+l*14+q = RX
    __shared__ float sRed[NW][NQ];

    const int tid = threadIdx.x;
    const int b = blockIdx.x;

    if (tid < 14) {
        float th = tanhf(x[b * NQ + tid]) * 1.57079632679489662f;
        sC[tid] = cosf(th); sS[tid] = sinf(th);
    } else if (tid < 56) {
        float th = w[tid - 14] * 0.5f;
        sC[tid] = cosf(th); sS[tid] = sinf(th);
    }

    const int pb1 = pad(TileR1::base_idx(tid));
    const int pb2 = pad(TileR2::base_idx(tid));
    const int pb3 = pad(TileR3::base_idx(tid));
    const int pb4 = pad(TileR4::base_idx(tid));

    __syncthreads();

    St st;

    // ================= layer 0 (embedding folded in) =================
    {   // R1: init |0..0> + RY q0-4 + RX q0-4 + chain CNOTs (no loads)
        cf2 cy0 = bcast(sC[0]), sy0 = bcast(sS[0]), cy1 = bcast(sC[1]), sy1 = bcast(sS[1]);
        cf2 cy2 = bcast(sC[2]), sy2 = bcast(sS[2]), cy3 = bcast(sC[3]), sy3 = bcast(sS[3]);
        cf2 cy4 = bcast(sC[4]), sy4 = bcast(sS[4]);
        cf2 cx0 = bcast(sC[14]), sx0 = bcast(sS[14]), cx1 = bcast(sC[15]), sx1 = bcast(sS[15]);
        cf2 cx2 = bcast(sC[16]), sx2 = bcast(sS[16]), cx3 = bcast(sC[17]), sx3 = bcast(sS[17]);
        cf2 cx4 = bcast(sC[18]), sx4 = bcast(sS[18]);
        sfor<TA>([&](auto jc) {
            constexpr int j = decltype(jc)::v;
            cf2 z; z.x = 0.f; z.y = 0.f;
            amp<j>(st) = z;
        });
        if (tid == 0) amp<0>(st).x = 1.f;
        g_ry<0>(st, cy4, sy4); g_ry<1>(st, cy3, sy3); g_ry<2>(st, cy2, sy2);
        g_ry<3>(st, cy1, sy1); g_ry<4>(st, cy0, sy0);
        g_rx<0>(st, cx4, sx4); g_rx<1>(st, cx3, sx3); g_rx<2>(st, cx2, sx2);
        g_rx<3>(st, cx1, sx1); g_rx<4>(st, cx0, sx0);
        g_cnot<4, 3>(st); g_cnot<3, 2>(st); g_cnot<2, 1>(st); g_cnot<1, 0>(st);
        store_tile<TileR1>(sSt, pb1, st);
    }
    __syncthreads();
    {   // R2: RY q5-8 + RX q5-8 + CNOT(q4,q5)..(q7,q8)
        cf2 cy5 = bcast(sC[5]), sy5 = bcast(sS[5]), cy6 = bcast(sC[6]), sy6 = bcast(sS[6]);
        cf2 cy7 = bcast(sC[7]), sy7 = bcast(sS[7]), cy8 = bcast(sC[8]), sy8 = bcast(sS[8]);
        cf2 cx5 = bcast(sC[19]), sx5 = bcast(sS[19]), cx6 = bcast(sC[20]), sx6 = bcast(sS[20]);
        cf2 cx7 = bcast(sC[21]), sx7 = bcast(sS[21]), cx8 = bcast(sC[22]), sx8 = bcast(sS[22]);
        load_tile<TileR2>(sSt, pb2, st);
        g_ry<0>(st, cy8, sy8); g_ry<1>(st, cy7, sy7); g_ry<2>(st, cy6, sy6); g_ry<3>(st, cy5, sy5);
        g_rx<0>(st, cx8, sx8); g_rx<1>(st, cx7, sx7); g_rx<2>(st, cx6, sx6); g_rx<3>(st, cx5, sx5);
        g_cnot<4, 3>(st); g_cnot<3, 2>(st); g_cnot<2, 1>(st); g_cnot<1, 0>(st);
        store_tile<TileR2>(sSt, pb2, st);
    }
    __syncthreads();
    {   // R3: RY q9-12 + RX q9-12 + CNOT(q8,q9)..(q11,q12)
        cf2 cy9 = bcast(sC[9]), sy9 = bcast(sS[9]), cyA = bcast(sC[10]), syA = bcast(sS[10]);
        cf2 cyB = bcast(sC[11]), syB = bcast(sS[11]), cyC = bcast(sC[12]), syC = bcast(sS[12]);
        cf2 cx9 = bcast(sC[23]), sx9 = bcast(sS[23]), cxA = bcast(sC[24]), sxA = bcast(sS[24]);
        cf2 cxB = bcast(sC[25]), sxB = bcast(sS[25]), cxC = bcast(sC[26]), sxC = bcast(sS[26]);
        load_tile<TileR3>(sSt, pb3, st);
        g_ry<0>(st, cyC, syC); g_ry<1>(st, cyB, syB); g_ry<2>(st, cyA, syA); g_ry<3>(st, cy9, sy9);
        g_rx<0>(st, cxC, sxC); g_rx<1>(st, cxB, sxB); g_rx<2>(st, cxA, sxA); g_rx<3>(st, cx9, sx9);
        g_cnot<4, 3>(st); g_cnot<3, 2>(st); g_cnot<2, 1>(st); g_cnot<1, 0>(st);
        store_tile<TileR3>(sSt, pb3, st);
    }
    __syncthreads();
    {   // R4: RY q13 + RX q13 + CNOT(q12,q13)(q13,q0)
        cf2 cyD = bcast(sC[13]), syD = bcast(sS[13]), cxD = bcast(sC[27]), sxD = bcast(sS[27]);
        load_tile<TileR4>(sSt, pb4, st);
        g_ry<0>(st, cyD, syD);
        g_rx<0>(st, cxD, sxD);
        g_cnot<1, 0>(st); g_cnot<0, 2>(st);
        store_tile<TileR4>(sSt, pb4, st);
    }
    __syncthreads();

    // ================= layers 1,2 =================
#pragma unroll 1
    for (int l = 1; l < 3; ++l) {
        const int s0 = 14 + l * NQ;
        {   // R1
            cf2 c0 = bcast(sC[s0 + 0]), t0 = bcast(sS[s0 + 0]);
            cf2 c1 = bcast(sC[s0 + 1]), t1 = bcast(sS[s0 + 1]);
            cf2 c2 = bcast(sC[s0 + 2]), t2 = bcast(sS[s0 + 2]);
            cf2 c3 = bcast(sC[s0 + 3]), t3 = bcast(sS[s0 + 3]);
            cf2 c4 = bcast(sC[s0 + 4]), t4 = bcast(sS[s0 + 4]);
            load_tile<TileR1>(sSt, pb1, st);
            g_rx<0>(st, c4, t4); g_rx<1>(st, c3, t3); g_rx<2>(st, c2, t2);
            g_rx<3>(st, c1, t1); g_rx<4>(st, c0, t0);
            g_cnot<4, 3>(st); g_cnot<3, 2>(st); g_cnot<2, 1>(st); g_cnot<1, 0>(st);
            store_tile<TileR1>(sSt, pb1, st);
        }
        __syncthreads();
        {   // R2
            cf2 c5 = bcast(sC[s0 + 5]), t5 = bcast(sS[s0 + 5]);
            cf2 c6 = bcast(sC[s0 + 6]), t6 = bcast(sS[s0 + 6]);
            cf2 c7 = bcast(sC[s0 + 7]), t7 = bcast(sS[s0 + 7]);
            cf2 c8 = bcast(sC[s0 + 8]), t8 = bcast(sS[s0 + 8]);
            load_tile<TileR2>(sSt, pb2, st);
            g_rx<0>(st, c8, t8); g_rx<1>(st, c7, t7); g_rx<2>(st, c6, t6); g_rx<3>(st, c5, t5);
            g_cnot<4, 3>(st); g_cnot<3, 2>(st); g_cnot<2, 1>(st); g_cnot<1, 0>(st);
            store_tile<TileR2>(sSt, pb2, st);
        }
        __syncthreads();
        {   // R3
            cf2 c9 = bcast(sC[s0 + 9]), t9 = bcast(sS[s0 + 9]);
            cf2 cA = bcast(sC[s0 + 10]), tA = bcast(sS[s0 + 10]);
            cf2 cB = bcast(sC[s0 + 11]), tB = bcast(sS[s0 + 11]);
            cf2 cC = bcast(sC[s0 + 12]), tC = bcast(sS[s0 + 12]);
            load_tile<TileR3>(sSt, pb3, st);
            g_rx<0>(st, cC, tC); g_rx<1>(st, cB, tB); g_rx<2>(st, cA, tA); g_rx<3>(st, c9, t9);
            g_cnot<4, 3>(st); g_cnot<3, 2>(st); g_cnot<2, 1>(st); g_cnot<1, 0>(st);
            store_tile<TileR3>(sSt, pb3, st);
        }
        __syncthreads();
        {   // R4
            cf2 cD = bcast(sC[s0 + 13]), tD = bcast(sS[s0 + 13]);
            load_tile<TileR4>(sSt, pb4, st);
            g_rx<0>(st, cD, tD);
            g_cnot<1, 0>(st); g_cnot<0, 2>(st);
            if (l == 1) store_tile<TileR4>(sSt, pb4, st);
        }
        if (l == 1) __syncthreads();
    }

    // ====== expvals from final registers (TileR4: l0=q13,l1=q12,l2=q0,l3=q1,l4=q2) ======
    float Stot = 0.f, S0 = 0.f, S1 = 0.f, S2 = 0.f, S3 = 0.f, S4 = 0.f;
    sfor<TA>([&](auto jc) {
        constexpr int j = decltype(jc)::v;
        cf2 v = amp<j>(st);
        float pj = v.x * v.x + v.y * v.y;
        Stot += pj;
        S0 += (j & 1)  ? -pj : pj;   // q13
        S1 += (j & 2)  ? -pj : pj;   // q12
        S2 += (j & 4)  ? -pj : pj;   // q0
        S3 += (j & 8)  ? -pj : pj;   // q1
        S4 += (j & 16) ? -pj : pj;   // q2
    });
    float ev[NQ];
    ev[0] = S2; ev[1] = S3; ev[2] = S4; ev[12] = S1; ev[13] = S0;
#pragma unroll
    for (int q = 3; q <= 11; ++q)    // q3..q11 <- tid bit (11-q)
        ev[q] = ((tid >> (11 - q)) & 1) ? -Stot : Stot;

#pragma unroll
    for (int q = 0; q < NQ; ++q) {
#pragma unroll
        for (int o = 32; o > 0; o >>= 1) ev[q] += __shfl_down(ev[q], o);
    }
    const int wv = tid >> 6, ln = tid & 63;
    if (ln == 0) {
#pragma unroll
        for (int q = 0; q < NQ; ++q) sRed[wv][q] = ev[q];
    }
    __syncthreads();
    if (tid < NQ) {
        float acc = 0.f;
#pragma unroll
        for (int k = 0; k < NW; ++k) acc += sRed[k][tid];
        out[b * NQ + tid] = acc;
    }
}

extern "C" void kernel_launch(void* const* d_in, const int* in_sizes, int n_in,
                              void* d_out, int out_size, void* d_ws, size_t ws_size,
                              hipStream_t stream) {
    const float* x = (const float*)d_in[0];   // (256, 14) float32
    const float* w = (const float*)d_in[1];   // (3, 14) float32
    float* out = (float*)d_out;               // (256, 14) float32
    qsim_kernel<<<256, NT, 0, stream>>>(x, w, out);
}